// Round 1
// baseline (357.187 us; speedup 1.0000x reference)
//
#include <hip/hip_runtime.h>

// PermutationCrossEntropy: preds [B,4,512] f32, targets [B,4] int -> out [B] f32
// out[b] = min over 24 perms sigma of -sum_p logsoftmax(preds[b,p])[targets[b,sigma(p)]]
//
// v2: persistent waves + 2-deep software pipeline.
// One wave per batch element as before (each 16-lane quarter owns one row,
// 32 elems/lane), but each wave now grid-strides over ~4 batches and issues
// the NEXT batch's 8 float4 loads + targets load BEFORE running the current
// batch's reduction tail (max/sum butterflies, gather, 24-perm min). The
// ~2-3K-cycle serial shuffle tail previously issued zero memory; now 9 loads
// stay in flight across it -> memory duty cycle rises from ~15% toward 100%.
// Memory-bound floor: 256 MB preds -> ~43 us at 6.3 TB/s.

// Permutations of (0,1,2,3), packed 2 bits per slot: sigma(p) in bits [2p,2p+1].
__device__ __constant__ unsigned char kPermPack[24] = {
    228, 180, 216, 120, 156, 108,   // 0123 0132 0213 0231 0312 0321
    225, 177, 201,  57, 141,  45,   // 1023 1032 1203 1230 1302 1320
    210, 114, 198,  54,  78,  30,   // 2013 2031 2103 2130 2301 2310
    147,  99, 135,  39,  75,  27    // 3012 3021 3102 3120 3201 3210
};

__device__ __forceinline__ float batch_loss(const float4 (&v)[8],
                                            const float* __restrict__ preds,
                                            int b, int q, int lane, int t) {
    // ---- row max: per-lane tree, then 4-step butterfly within the quarter ----
    float m = fmaxf(fmaxf(v[0].x, v[0].y), fmaxf(v[0].z, v[0].w));
#pragma unroll
    for (int j = 1; j < 8; ++j)
        m = fmaxf(m, fmaxf(fmaxf(v[j].x, v[j].y), fmaxf(v[j].z, v[j].w)));
#pragma unroll
    for (int off = 8; off; off >>= 1)
        m = fmaxf(m, __shfl_xor(m, off, 64));   // xor<16 stays inside quarter

    // ---- sum(exp(x - max)), 4-step butterfly within the quarter ----
    float s = 0.0f;
#pragma unroll
    for (int j = 0; j < 8; ++j)
        s += __expf(v[j].x - m) + __expf(v[j].y - m) +
             __expf(v[j].z - m) + __expf(v[j].w - m);
#pragma unroll
    for (int off = 8; off; off >>= 1)
        s += __shfl_xor(s, off, 64);

    const float lse = m + __logf(s);   // resident in every lane of quarter q

    // ---- gather g = logp[b, q, t]; lane p*16+j holds G[p][j].
    // L2-hot: this wave streamed the row one pipeline stage ago.
    const float g = preds[(size_t)b * 2048 + q * 512 + t] - lse;

    // ---- 24 permutation sums (lanes >=24 duplicate perm 0) ----
    const int kk = (lane < 24) ? lane : 0;
    const unsigned pack = kPermPack[kk];
    float loss = 0.0f;
#pragma unroll
    for (int p = 0; p < 4; ++p) {
        const int j = (pack >> (2 * p)) & 3;
        loss -= __shfl(g, (p << 4) + j, 64);   // ds_bpermute, per-lane source
    }
    // min over lanes 0..31 covers all 24 perms
#pragma unroll
    for (int off = 16; off; off >>= 1)
        loss = fminf(loss, __shfl_xor(loss, off, 64));
    return loss;
}

__global__ __launch_bounds__(256, 4) void pce_kernel(
        const float* __restrict__ preds,
        const int* __restrict__ targets,
        float* __restrict__ out,
        int nb) {
    const int lane = threadIdx.x & 63;
    const int wv   = threadIdx.x >> 6;
    const int q    = lane >> 4;   // row owned by this quarter-wave
    const int l16  = lane & 15;
    const int nw   = gridDim.x * 4;         // total waves = batch stride

    int b = blockIdx.x * 4 + wv;
    if (b >= nb) return;   // wave-uniform exit

    const float4* pb4 = reinterpret_cast<const float4*>(preds);

    // ---- prologue: load batch b (coalesced; quarter q reads row q) ----
    float4 cur[8];
    {
        const float4* base = pb4 + (size_t)b * 512 + q * 128 + l16;
#pragma unroll
        for (int j = 0; j < 8; ++j) cur[j] = base[16 * j];
    }
    int t = targets[(size_t)b * 4 + (lane & 3)];

    while (true) {
        // ---- issue next batch's loads BEFORE the serial reduction tail ----
        const int bn = b + nw;
        const bool have_next = (bn < nb);   // wave-uniform
        float4 nxt[8];
        int tn = 0;
        if (have_next) {
            const float4* base = pb4 + (size_t)bn * 512 + q * 128 + l16;
#pragma unroll
            for (int j = 0; j < 8; ++j) nxt[j] = base[16 * j];
            tn = targets[(size_t)bn * 4 + (lane & 3)];
        }

        // ---- compute current batch while next batch's loads are in flight ----
        const float loss = batch_loss(cur, preds, b, q, lane, t);
        if (lane == 0) out[b] = loss;

        if (!have_next) break;   // wave-uniform
#pragma unroll
        for (int j = 0; j < 8; ++j) cur[j] = nxt[j];   // 32 v_mov, ~2% of stage
        t = tn;
        b = bn;
    }
}

extern "C" void kernel_launch(void* const* d_in, const int* in_sizes, int n_in,
                              void* d_out, int out_size, void* d_ws, size_t ws_size,
                              hipStream_t stream) {
    const float* preds   = (const float*)d_in[0];
    const int*   targets = (const int*)d_in[1];
    float*       out     = (float*)d_out;
    const int nb = in_sizes[0] / 2048;          // B = elems / (P*C)
    int blocks = (nb + 3) / 4;                  // 4 waves (batch elems) per block
    if (blocks > 2048) blocks = 2048;           // persistent: ~4 batches per wave
    hipLaunchKernelGGL(pce_kernel, dim3(blocks), dim3(256), 0, stream,
                       preds, targets, out, nb);
}